// Round 20
// baseline (201.009 us; speedup 1.0000x reference)
//
#include <hip/hip_runtime.h>
#include <hip/hip_bf16.h>

// Swin3D block, MI355X. k1234: LN1+QKV+attn+proj+residual, one block/window.
// Round-19 + transposed-MFMA packed stores in phases B(Q,K) and D, and a
// vectorized staged residual epilogue (1 src_tok per row instead of 28/lane).
// k567: LN2+MLP, single-buffered block-staged weights (66.5 KB -> 2 blocks/CU).
// fp32 residual spine lives in d_out.

typedef __bf16 bf16x8 __attribute__((ext_vector_type(8)));
typedef __bf16 bf16x4 __attribute__((ext_vector_type(4)));
typedef float f32x4 __attribute__((ext_vector_type(4)));

#define SCALE_Q 0.17677669529663687f
#define LOG2E   1.4426950408889634f
#define SCALE_QE (SCALE_Q * LOG2E)

static __device__ __forceinline__ f32x4 mfma16(bf16x8 a, bf16x8 b, f32x4 c) {
  return __builtin_amdgcn_mfma_f32_16x16x32_bf16(a, b, c, 0, 0, 0);
}

static __device__ __forceinline__ float fast_exp2(float x) {
#if __has_builtin(__builtin_amdgcn_exp2f)
  return __builtin_amdgcn_exp2f(x);
#else
  return exp2f(x);
#endif
}
static __device__ __forceinline__ float fast_rcp(float x) {
#if __has_builtin(__builtin_amdgcn_rcpf)
  return __builtin_amdgcn_rcpf(x);
#else
  return 1.f / x;
#endif
}

// tanh-approx GELU in sigmoid form. |err| vs exact < 1e-3 (contracted by FC2).
static __device__ __forceinline__ float fast_gelu(float x) {
  float e = fast_exp2(x * fmaf(-0.1029445213f, x * x, -2.3022077385f));
  return x * fast_rcp(1.f + e);
}

// window wi (0..2047), token n (0..97) -> flat spatial token index in x (rolled by +1,+3,+3)
static __device__ __forceinline__ int src_tok(int wi, int n) {
  int b = wi >> 10, r = wi & 1023;
  int d0 = r >> 8, h0 = (r >> 4) & 15, w0 = r & 15;
  int dd = n / 49, rem = n - dd * 49, hh = rem / 7, ww = rem - hh * 7;
  int d = (d0 * 2 + dd + 1) & 7;
  int h = h0 * 7 + hh + 3; if (h >= 112) h -= 112;
  int w = w0 * 7 + ww + 3; if (w >= 112) w -= 112;
  return ((b * 8 + d) * 112 + h) * 112 + w;
}

// region id in the SHIFTED frame, parameterized by window class bits
// (bit2: d0==3, bit1: h0==15, bit0: w0==15). Valid for n in [0,112).
static __device__ __forceinline__ int region_cls(int cls, int n) {
  int dd = n / 49, rem = n - dd * 49, hh = rem / 7, ww = rem - hh * 7;
  int dr = (cls & 4) ? dd + 1 : 0;
  int hr = (cls & 2) ? (hh < 4 ? 1 : 2) : 0;
  int wr = (cls & 1) ? (ww < 4 ? 1 : 2) : 0;
  return dr * 9 + hr * 3 + wr;
}

// ---------------- K0: weight prep + MFMA-fragment-ordered bias table ----------------
__global__ __launch_bounds__(256) void k0_prep(
    const float* __restrict__ qkv_w, const float* __restrict__ qkv_b,
    const float* __restrict__ rpb, const float* __restrict__ proj_w,
    const float* __restrict__ fc1_w, const float* __restrict__ fc2_w,
    __bf16* __restrict__ wqkv, float* __restrict__ qkvb_s,
    __bf16* __restrict__ wproj, __bf16* __restrict__ wfc1, __bf16* __restrict__ wfc2,
    float* __restrict__ biasF) {
  int idx = blockIdx.x * 256 + threadIdx.x;
  if (idx < 27648) { // qkv_w (288x96): fold q-scale * log2e into q rows
    int row = idx / 96; float v = qkv_w[idx];
    wqkv[idx] = (__bf16)(row < 96 ? v * SCALE_QE : v); return;
  }
  idx -= 27648;
  if (idx < 9216) { wproj[idx] = (__bf16)proj_w[idx]; return; }
  idx -= 9216;
  if (idx < 36864) { wfc1[idx] = (__bf16)fc1_w[idx]; return; }
  idx -= 36864;
  if (idx < 36864) { wfc2[idx] = (__bf16)fc2_w[idx]; return; }
  idx -= 36864;
  if (idx < 288) { float v = qkv_b[idx]; qkvb_s[idx] = idx < 96 ? v * SCALE_QE : v; return; }
  idx -= 288;
  if (idx < 301056) { // 8*3*49*64*4
    int j = idx & 3, lane = (idx >> 2) & 63, t = idx >> 8;
    int nt = t % 7, mt = (t / 7) % 7, hd = (t / 49) % 3, cls = t / 147;
    int i = 16 * mt + 4 * (lane >> 4) + j;   // query row 0..111
    int jt = 16 * nt + (lane & 15);          // key col 0..111
    float v;
    if (jt >= 98) {
      v = -1e30f;                            // pad mask: exp2 -> 0
    } else {
      float rp = 0.f;
      if (i < 98) {
        int di = i / 49, ri_ = i - di * 49, hi = ri_ / 7, wi_ = ri_ - hi * 7;
        int dj = jt / 49, rj_ = jt - dj * 49, hj = rj_ / 7, wj = rj_ - hj * 7;
        int rpi = (di - dj + 1) * 169 + (hi - hj + 6) * 13 + (wi_ - wj + 6);
        rp = rpb[rpi * 3 + hd];
      }
      float mk = (region_cls(cls, i) != region_cls(cls, jt)) ? -100.f : 0.f;
      v = (rp + mk) * LOG2E;
    }
    biasF[idx] = v;
  }
}

// ---------------- K1234: LN1 + roll + QKV + attention + proj + residual ----------------
__global__ __launch_bounds__(512, 1) void k1234_attn(
    const float* __restrict__ x, const float* __restrict__ n1w, const float* __restrict__ n1b,
    const __bf16* __restrict__ wqkv, const float* __restrict__ qkvb,
    const f32x4* __restrict__ biasF, const __bf16* __restrict__ wproj,
    const float* __restrict__ projb, float* __restrict__ x2) {
  int wi = blockIdx.x;
  int tid = threadIdx.x;
  int wave = tid >> 6, l = tid & 63, col = l & 15, gq = l >> 4;
  __shared__ __bf16 win_lds[112][104];            // A out / B in; C writes attnO; D reads
  __shared__ __align__(16) __bf16 QK_lds[2][112][104];  // Q, K; stage overlay in D
  __shared__ __bf16 Vt_lds[96][136];              // dims x tokens; 112..127 zeroed
  __shared__ __bf16 p_lds[8][16][136];            // per-wave P tile
  auto& Q_lds = QK_lds[0];
  auto& K_lds = QK_lds[1];
  float (*stage)[100] = (float(*)[100])QK_lds;    // 44.8 KB <= 46.6 KB, Q/K dead in D

  // ---- phase A: LN1 + roll-gather (packed b128 stores) ----
  if (tid < 392) {
    int row = tid >> 2, cq = (tid & 3) * 24;
    const float* src = x + (size_t)src_tok(wi, row) * 96 + cq;
    float v[24];
    float sm = 0.f, sq = 0.f;
#pragma unroll
    for (int i = 0; i < 6; i++) {
      f32x4 u = *(const f32x4*)(src + 4 * i);
#pragma unroll
      for (int k = 0; k < 4; k++) { v[4 * i + k] = u[k]; sm += u[k]; sq += u[k] * u[k]; }
    }
    sm += __shfl_xor(sm, 1); sq += __shfl_xor(sq, 1);
    sm += __shfl_xor(sm, 2); sq += __shfl_xor(sq, 2);
    float mean = sm * (1.f / 96.f);
    float rstd = rsqrtf(sq * (1.f / 96.f) - mean * mean + 1e-5f);
    __bf16 outv[24];
#pragma unroll
    for (int i = 0; i < 24; i++)
      outv[i] = (__bf16)((v[i] - mean) * rstd * n1w[cq + i] + n1b[cq + i]);
#pragma unroll
    for (int i = 0; i < 3; i++)
      *(bf16x8*)&win_lds[row][cq + 8 * i] = *(bf16x8*)&outv[8 * i];
  } else {
    int z = tid - 392;  // 120 threads: zero pad rows of win, pad token-cols of Vt
    for (int e = z; e < 1344; e += 120) { int r = e / 96; win_lds[98 + r][e - r * 96] = (__bf16)0.f; }
    for (int e = z; e < 1536; e += 120) Vt_lds[e >> 4][112 + (e & 15)] = (__bf16)0.f;
  }
  __syncthreads();

  // ---- phase B: QKV GEMM (waves 0..5) ----
  // Waves 0-3 (Q,K): TRANSPOSED mfma(bb, a) -> lane holds 4 consecutive output
  // dims for one token -> packed b64 stores (21 vs 84 scalar). Waves 4-5 (V):
  // original orientation, token-packed b64 stores into dim-major Vt.
  if (wave < 6) {
    f32x4 acc[7][3] = {};
    bool isQK = (wave < 4);
#pragma unroll
    for (int kk = 0; kk < 3; kk++) {
      bf16x8 a[7], bb[3];
#pragma unroll
      for (int mt = 0; mt < 7; mt++)
        a[mt] = *(const bf16x8*)&win_lds[16 * mt + col][32 * kk + 8 * gq];
#pragma unroll
      for (int t = 0; t < 3; t++)
        bb[t] = *(const bf16x8*)(wqkv + (size_t)(wave * 48 + 16 * t + col) * 96 + 32 * kk + 8 * gq);
#pragma unroll
      for (int mt = 0; mt < 7; mt++)
#pragma unroll
        for (int t = 0; t < 3; t++)
          acc[mt][t] = isQK ? mfma16(bb[t], a[mt], acc[mt][t])
                            : mfma16(a[mt], bb[t], acc[mt][t]);
    }
    if (isQK) {
      // lane: token = 16mt+col, dims n = wave*48+16t+4gq+j (4 consecutive)
#pragma unroll
      for (int t = 0; t < 3; t++) {
        int nb = wave * 48 + 16 * t + 4 * gq;
        f32x4 b4 = *(const f32x4*)(qkvb + nb);
        int isK = nb >= 96;
        int cb = nb - (isK ? 96 : 0);
#pragma unroll
        for (int mt = 0; mt < 7; mt++) {
          bf16x4 pk;
#pragma unroll
          for (int j = 0; j < 4; j++) pk[j] = (__bf16)(acc[mt][t][j] + b4[j]);
          if (isK) *(bf16x4*)&K_lds[16 * mt + col][cb] = pk;
          else     *(bf16x4*)&Q_lds[16 * mt + col][cb] = pk;
        }
      }
    } else {
      // V: lane holds 4 consecutive tokens for one dim -> pack along tokens
#pragma unroll
      for (int t = 0; t < 3; t++) {
        int n = wave * 48 + 16 * t + col;
        float bias = qkvb[n];
        int c = n - 192;
#pragma unroll
        for (int mt = 0; mt < 7; mt++) {
          bf16x4 pk;
#pragma unroll
          for (int j = 0; j < 4; j++) pk[j] = (__bf16)(acc[mt][t][j] + bias);
          *(bf16x4*)&Vt_lds[c][16 * mt + 4 * gq] = pk;
        }
      }
    }
  }
  __syncthreads();

  // ---- phase C: attention, 21 (head,mt) tiles over 8 waves (max 3 each) ----
  {
    {
      int rr = l >> 2, cc = 112 + ((l & 3) << 2);
      *(uint2*)&p_lds[wave][rr][cc] = make_uint2(0u, 0u);
    }
    int cls = ((((wi >> 8) & 3) == 3) ? 4 : 0) | ((((wi >> 4) & 15) == 15) ? 2 : 0) |
              (((wi & 15) == 15) ? 1 : 0);
    int ntiles = (wave < 6) ? 3 : (wave == 6 ? 2 : 1);
    bf16x8 kf[7], vf[2][4];
    int cur_hd = -1;
#pragma unroll 1
    for (int s = 0; s < ntiles; s++) {
      int hd, mt;
      if (wave < 6)      { hd = wave >> 1; mt = ((wave & 1) ? 4 : 0) + s; }
      else if (wave == 6){ hd = s;         mt = 3; }
      else               { hd = 2;         mt = 3; }
      if (hd != cur_hd) {
        cur_hd = hd;
#pragma unroll
        for (int nt = 0; nt < 7; nt++)
          kf[nt] = *(const bf16x8*)&K_lds[16 * nt + col][hd * 32 + 8 * gq];
#pragma unroll
        for (int nt = 0; nt < 2; nt++)
#pragma unroll
          for (int ks = 0; ks < 4; ks++)
            vf[nt][ks] = *(const bf16x8*)&Vt_lds[hd * 32 + 16 * nt + col][32 * ks + 8 * gq];
      }
      const f32x4* bfr = biasF + (size_t)((cls * 3 + hd) * 49) * 64 + l;
      bf16x8 qf = *(const bf16x8*)&Q_lds[16 * mt + col][hd * 32 + 8 * gq];
      float sum0 = 0.f, sum1 = 0.f, sum2 = 0.f, sum3 = 0.f;
#pragma unroll
      for (int nt = 0; nt < 7; nt++) {
        f32x4 sv = mfma16(qf, kf[nt], bfr[(mt * 7 + nt) * 64]);
        float e0 = fast_exp2(sv[0]); sum0 += e0;
        float e1 = fast_exp2(sv[1]); sum1 += e1;
        float e2 = fast_exp2(sv[2]); sum2 += e2;
        float e3 = fast_exp2(sv[3]); sum3 += e3;
        p_lds[wave][4 * gq + 0][16 * nt + col] = (__bf16)e0;
        p_lds[wave][4 * gq + 1][16 * nt + col] = (__bf16)e1;
        p_lds[wave][4 * gq + 2][16 * nt + col] = (__bf16)e2;
        p_lds[wave][4 * gq + 3][16 * nt + col] = (__bf16)e3;
      }
#pragma unroll
      for (int m = 1; m < 16; m <<= 1) {
        sum0 += __shfl_xor(sum0, m, 16);
        sum1 += __shfl_xor(sum1, m, 16);
        sum2 += __shfl_xor(sum2, m, 16);
        sum3 += __shfl_xor(sum3, m, 16);
      }
      f32x4 oacc0 = {}, oacc1 = {};
#pragma unroll
      for (int ks = 0; ks < 4; ks++) {
        bf16x8 pa = *(const bf16x8*)&p_lds[wave][col][32 * ks + 8 * gq];
        oacc0 = mfma16(pa, vf[0][ks], oacc0);
        oacc1 = mfma16(pa, vf[1][ks], oacc1);
      }
      float inv0 = fast_rcp(sum0), inv1 = fast_rcp(sum1), inv2 = fast_rcp(sum2), inv3 = fast_rcp(sum3);
      int ibase = 16 * mt + 4 * gq;
      // attnO -> win_lds (win dead after phase B)
      win_lds[ibase + 0][hd * 32 + col]      = (__bf16)(oacc0[0] * inv0);
      win_lds[ibase + 1][hd * 32 + col]      = (__bf16)(oacc0[1] * inv1);
      win_lds[ibase + 2][hd * 32 + col]      = (__bf16)(oacc0[2] * inv2);
      win_lds[ibase + 3][hd * 32 + col]      = (__bf16)(oacc0[3] * inv3);
      win_lds[ibase + 0][hd * 32 + 16 + col] = (__bf16)(oacc1[0] * inv0);
      win_lds[ibase + 1][hd * 32 + 16 + col] = (__bf16)(oacc1[1] * inv1);
      win_lds[ibase + 2][hd * 32 + 16 + col] = (__bf16)(oacc1[2] * inv2);
      win_lds[ibase + 3][hd * 32 + 16 + col] = (__bf16)(oacc1[3] * inv3);
    }
  }
  __syncthreads();

  // ---- phase D1: proj (transposed mfma) -> fp32 stage over dead Q/K region ----
  if (wave < 6) {
    f32x4 acc[7] = {};
#pragma unroll
    for (int kk = 0; kk < 3; kk++) {
      bf16x8 bb = *(const bf16x8*)(wproj + (size_t)(16 * wave + col) * 96 + 32 * kk + 8 * gq);
#pragma unroll
      for (int mt = 0; mt < 7; mt++) {
        bf16x8 a = *(const bf16x8*)&win_lds[16 * mt + col][32 * kk + 8 * gq];
        acc[mt] = mfma16(bb, a, acc[mt]);   // transposed: lane = (c=16w+4gq+j, token=16mt+col)
      }
    }
    f32x4 pb4 = *(const f32x4*)(projb + 16 * wave + 4 * gq);
#pragma unroll
    for (int mt = 0; mt < 7; mt++) {
      f32x4 o;
#pragma unroll
      for (int j = 0; j < 4; j++) o[j] = acc[mt][j] + pb4[j];
      *(f32x4*)&stage[16 * mt + col][16 * wave + 4 * gq] = o;
    }
  }
  __syncthreads();

  // ---- phase D2: vectorized residual epilogue (1 src_tok per row) ----
  if (tid < 392) {
    int row = tid >> 2, cq = (tid & 3) * 24;
    size_t s = (size_t)src_tok(wi, row);
    const float* xs = x + s * 96 + cq;
    float* xd = x2 + s * 96 + cq;
#pragma unroll
    for (int i = 0; i < 6; i++) {
      f32x4 u = *(const f32x4*)(xs + 4 * i);
      f32x4 st = *(const f32x4*)&stage[row][cq + 4 * i];
      f32x4 r;
#pragma unroll
      for (int k = 0; k < 4; k++) r[k] = u[k] + st[k];
      *(f32x4*)(xd + 4 * i) = r;
    }
  }
}

// ---------------- K567: fused LN2 + FC1 + GELU + FC2 + residual ----------------
// 128-row blocks (grid 1568), single-buffered weight staging, 66.5 KB -> 2 blocks/CU.
__global__ __launch_bounds__(512, 2) void k567_mlp(
    const float* __restrict__ n2w, const float* __restrict__ n2b,
    const __bf16* __restrict__ wfc1, const float* __restrict__ fc1b,
    const __bf16* __restrict__ wfc2, const float* __restrict__ fc2b,
    float* __restrict__ x2) {
  int tid = threadIdx.x;
  int wave = tid >> 6, l = tid & 63, col = l & 15, gq = l >> 4;
  size_t rowbase = (size_t)blockIdx.x * 128 + wave * 16;
  __shared__ __bf16 wbuf[2][96][104];  // [W1/W2][row][col pad 104]
  __shared__ __bf16 htl[8][16][104];   // wave-private hidden tile

  // ---- LN2 -> register A-fragments (row col of this wave's 16) ----
  bf16x8 afr[3];
  {
    float v[24];
    float sm = 0.f, sq = 0.f;
    const float* src = x2 + (rowbase + col) * 96 + 8 * gq;
#pragma unroll
    for (int kk = 0; kk < 3; kk++) {
      f32x4 u0 = *(const f32x4*)(src + 32 * kk);
      f32x4 u1 = *(const f32x4*)(src + 32 * kk + 4);
#pragma unroll
      for (int k = 0; k < 4; k++) {
        v[8 * kk + k] = u0[k];     sm += u0[k]; sq += u0[k] * u0[k];
        v[8 * kk + 4 + k] = u1[k]; sm += u1[k]; sq += u1[k] * u1[k];
      }
    }
    sm += __shfl_xor(sm, 16); sq += __shfl_xor(sq, 16);
    sm += __shfl_xor(sm, 32); sq += __shfl_xor(sq, 32);
    float mean = sm * (1.f / 96.f);
    float rstd = rsqrtf(sq * (1.f / 96.f) - mean * mean + 1e-5f);
#pragma unroll
    for (int kk = 0; kk < 3; kk++) {
      f32x4 w0 = *(const f32x4*)(n2w + 32 * kk + 8 * gq);
      f32x4 w1 = *(const f32x4*)(n2w + 32 * kk + 8 * gq + 4);
      f32x4 b0 = *(const f32x4*)(n2b + 32 * kk + 8 * gq);
      f32x4 b1 = *(const f32x4*)(n2b + 32 * kk + 8 * gq + 4);
#pragma unroll
      for (int k = 0; k < 4; k++) {
        afr[kk][k]     = (__bf16)((v[8 * kk + k]     - mean) * rstd * w0[k] + b0[k]);
        afr[kk][4 + k] = (__bf16)((v[8 * kk + 4 + k] - mean) * rstd * w1[k] + b1[k]);
      }
    }
  }

  // cooperative weight staging: 2304 16B units per quarter (1152 W1 + 1152 W2)
#define STAGE_LOAD(qq, st)                                                        \
  {                                                                               \
    _Pragma("unroll")                                                             \
    for (int i = 0; i < 4; i++) {                                                 \
      int u = tid + 512 * i;                                                      \
      int which = u >= 1152; int uu = u - which * 1152;                           \
      int row = uu / 12, c = uu - row * 12;                                       \
      const __bf16* g = which ? (wfc2 + (size_t)row * 384 + (qq) * 96 + c * 8)    \
                              : (wfc1 + ((size_t)((qq) * 96 + row)) * 96 + c * 8);\
      st[i] = *(const bf16x8*)g;                                                  \
    }                                                                             \
    if (tid < 256) {                                                              \
      int u = 2048 + tid;                                                         \
      int row = (u - 1152) / 12, c = (u - 1152) - row * 12;                       \
      st[4] = *(const bf16x8*)(wfc2 + (size_t)row * 384 + (qq) * 96 + c * 8);     \
    }                                                                             \
  }
#define STAGE_WRITE(st)                                                           \
  {                                                                               \
    _Pragma("unroll")                                                             \
    for (int i = 0; i < 4; i++) {                                                 \
      int u = tid + 512 * i;                                                      \
      int which = u >= 1152; int uu = u - which * 1152;                           \
      int row = uu / 12, c = uu - row * 12;                                       \
      *(bf16x8*)&wbuf[which][row][c * 8] = st[i];                                 \
    }                                                                             \
    if (tid < 256) {                                                              \
      int u = 2048 + tid;                                                         \
      int row = (u - 1152) / 12, c = (u - 1152) - row * 12;                       \
      *(bf16x8*)&wbuf[1][row][c * 8] = st[4];                                     \
    }                                                                             \
  }

  // prologue: stage quarter 0
  {
    bf16x8 st[5];
    STAGE_LOAD(0, st);
    STAGE_WRITE(st);
  }
  __syncthreads();

  f32x4 oc[6] = {};
#pragma unroll 1
  for (int q = 0; q < 4; q++) {
    bf16x8 st[5];
    if (q < 3) STAGE_LOAD(q + 1, st);      // issue early: hides under MFMA
    // ---- stage 1: acc = ntile @ W1_q^T ----
    f32x4 acc[6] = {};
#pragma unroll
    for (int kk = 0; kk < 3; kk++) {
      bf16x8 bb[6];
#pragma unroll
      for (int t = 0; t < 6; t++)
        bb[t] = *(const bf16x8*)&wbuf[0][16 * t + col][32 * kk + 8 * gq];
#pragma unroll
      for (int t = 0; t < 6; t++) acc[t] = mfma16(afr[kk], bb[t], acc[t]);
    }
    // ---- gelu -> wave-private htl ----
#pragma unroll
    for (int t = 0; t < 6; t++) {
      float bv = fc1b[q * 96 + 16 * t + col];
#pragma unroll
      for (int j = 0; j < 4; j++)
        htl[wave][4 * gq + j][16 * t + col] = (__bf16)fast_gelu(acc[t][j] + bv);
    }
    // ---- stage 2: oc += htl @ W2_q^T ----
#pragma unroll
    for (int kk = 0; kk < 3; kk++) {
      bf16x8 a0 = *(const bf16x8*)&htl[wave][col][32 * kk + 8 * gq];
      bf16x8 bb[6];
#pragma unroll
      for (int t = 0; t < 6; t++)
        bb[t] = *(const bf16x8*)&wbuf[1][16 * t + col][32 * kk + 8 * gq];
#pragma unroll
      for (int t = 0; t < 6; t++) oc[t] = mfma16(a0, bb[t], oc[t]);
    }
    __syncthreads();                       // all waves done READING wbuf for q
    if (q < 3) {
      STAGE_WRITE(st);                     // overwrite with quarter q+1
      __syncthreads();                     // wbuf ready
    }
  }
  // ---- epilogue: x2 += oc + b2 ----
#pragma unroll
  for (int t = 0; t < 6; t++) {
    float bv = fc2b[16 * t + col];
#pragma unroll
    for (int j = 0; j < 4; j++) {
      size_t row = rowbase + 4 * gq + j;
      x2[row * 96 + 16 * t + col] = x2[row * 96 + 16 * t + col] + oc[t][j] + bv;
    }
  }
#undef STAGE_LOAD
#undef STAGE_WRITE
}

// ---------------- launcher ----------------
// ws layout (bytes):
#define O_WQKV   0L
#define O_WPROJ  55296L
#define O_WFC1   73728L
#define O_WFC2   147456L
#define O_QKVB   221184L
#define O_BIASF  222336L     // 1,204,224 B

extern "C" void kernel_launch(void* const* d_in, const int* in_sizes, int n_in,
                              void* d_out, int out_size, void* d_ws, size_t ws_size,
                              hipStream_t stream) {
  const float* x     = (const float*)d_in[0];
  const float* n1w   = (const float*)d_in[1];
  const float* n1b   = (const float*)d_in[2];
  const float* qkvw  = (const float*)d_in[3];
  const float* qkvb  = (const float*)d_in[4];
  const float* rpb   = (const float*)d_in[5];
  const float* projw = (const float*)d_in[6];
  const float* projb = (const float*)d_in[7];
  const float* n2w   = (const float*)d_in[8];
  const float* n2b   = (const float*)d_in[9];
  const float* fc1w  = (const float*)d_in[10];
  const float* fc1b  = (const float*)d_in[11];
  const float* fc2w  = (const float*)d_in[12];
  const float* fc2b  = (const float*)d_in[13];

  char* ws = (char*)d_ws;
  __bf16* wqkv   = (__bf16*)(ws + O_WQKV);
  __bf16* wproj  = (__bf16*)(ws + O_WPROJ);
  __bf16* wfc1   = (__bf16*)(ws + O_WFC1);
  __bf16* wfc2   = (__bf16*)(ws + O_WFC2);
  float*  qkvb_s = (float*)(ws + O_QKVB);
  float*  biasF  = (float*)(ws + O_BIASF);
  float*  x2     = (float*)d_out;          // residual spine lives in d_out

  k0_prep<<<1610, 256, 0, stream>>>(qkvw, qkvb, rpb, projw, fc1w, fc2w,
                                    wqkv, qkvb_s, wproj, wfc1, wfc2, biasF);
  k1234_attn<<<2048, 512, 0, stream>>>(x, n1w, n1b, wqkv, qkvb_s,
                                       (const f32x4*)biasF, wproj, projb, x2);
  k567_mlp<<<1568, 512, 0, stream>>>(n2w, n2b, wfc1, fc1b, wfc2, fc2b, x2);
}

// Round 21
// 190.936 us; speedup vs baseline: 1.0528x; 1.0528x over previous
//
#include <hip/hip_runtime.h>
#include <hip/hip_bf16.h>

// Swin3D block, MI355X. k1234: round-19 structure (packed phase-A stores,
// packed V stores, direct phase-D scatter) + transposed-MFMA packed Q/K stores
// in phase B (the only change vs round 19 -- clean A/B).
// k567: LN2+MLP, single-buffered block-staged weights (66.5 KB -> 2 blocks/CU).
// fp32 residual spine lives in d_out.

typedef __bf16 bf16x8 __attribute__((ext_vector_type(8)));
typedef __bf16 bf16x4 __attribute__((ext_vector_type(4)));
typedef float f32x4 __attribute__((ext_vector_type(4)));

#define SCALE_Q 0.17677669529663687f
#define LOG2E   1.4426950408889634f
#define SCALE_QE (SCALE_Q * LOG2E)

static __device__ __forceinline__ f32x4 mfma16(bf16x8 a, bf16x8 b, f32x4 c) {
  return __builtin_amdgcn_mfma_f32_16x16x32_bf16(a, b, c, 0, 0, 0);
}

static __device__ __forceinline__ float fast_exp2(float x) {
#if __has_builtin(__builtin_amdgcn_exp2f)
  return __builtin_amdgcn_exp2f(x);
#else
  return exp2f(x);
#endif
}
static __device__ __forceinline__ float fast_rcp(float x) {
#if __has_builtin(__builtin_amdgcn_rcpf)
  return __builtin_amdgcn_rcpf(x);
#else
  return 1.f / x;
#endif
}

// tanh-approx GELU in sigmoid form. |err| vs exact < 1e-3 (contracted by FC2).
static __device__ __forceinline__ float fast_gelu(float x) {
  float e = fast_exp2(x * fmaf(-0.1029445213f, x * x, -2.3022077385f));
  return x * fast_rcp(1.f + e);
}

// window wi (0..2047), token n (0..97) -> flat spatial token index in x (rolled by +1,+3,+3)
static __device__ __forceinline__ int src_tok(int wi, int n) {
  int b = wi >> 10, r = wi & 1023;
  int d0 = r >> 8, h0 = (r >> 4) & 15, w0 = r & 15;
  int dd = n / 49, rem = n - dd * 49, hh = rem / 7, ww = rem - hh * 7;
  int d = (d0 * 2 + dd + 1) & 7;
  int h = h0 * 7 + hh + 3; if (h >= 112) h -= 112;
  int w = w0 * 7 + ww + 3; if (w >= 112) w -= 112;
  return ((b * 8 + d) * 112 + h) * 112 + w;
}

// region id in the SHIFTED frame, parameterized by window class bits
// (bit2: d0==3, bit1: h0==15, bit0: w0==15). Valid for n in [0,112).
static __device__ __forceinline__ int region_cls(int cls, int n) {
  int dd = n / 49, rem = n - dd * 49, hh = rem / 7, ww = rem - hh * 7;
  int dr = (cls & 4) ? dd + 1 : 0;
  int hr = (cls & 2) ? (hh < 4 ? 1 : 2) : 0;
  int wr = (cls & 1) ? (ww < 4 ? 1 : 2) : 0;
  return dr * 9 + hr * 3 + wr;
}

// ---------------- K0: weight prep + MFMA-fragment-ordered bias table ----------------
__global__ __launch_bounds__(256) void k0_prep(
    const float* __restrict__ qkv_w, const float* __restrict__ qkv_b,
    const float* __restrict__ rpb, const float* __restrict__ proj_w,
    const float* __restrict__ fc1_w, const float* __restrict__ fc2_w,
    __bf16* __restrict__ wqkv, float* __restrict__ qkvb_s,
    __bf16* __restrict__ wproj, __bf16* __restrict__ wfc1, __bf16* __restrict__ wfc2,
    float* __restrict__ biasF) {
  int idx = blockIdx.x * 256 + threadIdx.x;
  if (idx < 27648) { // qkv_w (288x96): fold q-scale * log2e into q rows
    int row = idx / 96; float v = qkv_w[idx];
    wqkv[idx] = (__bf16)(row < 96 ? v * SCALE_QE : v); return;
  }
  idx -= 27648;
  if (idx < 9216) { wproj[idx] = (__bf16)proj_w[idx]; return; }
  idx -= 9216;
  if (idx < 36864) { wfc1[idx] = (__bf16)fc1_w[idx]; return; }
  idx -= 36864;
  if (idx < 36864) { wfc2[idx] = (__bf16)fc2_w[idx]; return; }
  idx -= 36864;
  if (idx < 288) { float v = qkv_b[idx]; qkvb_s[idx] = idx < 96 ? v * SCALE_QE : v; return; }
  idx -= 288;
  if (idx < 301056) { // 8*3*49*64*4
    int j = idx & 3, lane = (idx >> 2) & 63, t = idx >> 8;
    int nt = t % 7, mt = (t / 7) % 7, hd = (t / 49) % 3, cls = t / 147;
    int i = 16 * mt + 4 * (lane >> 4) + j;   // query row 0..111
    int jt = 16 * nt + (lane & 15);          // key col 0..111
    float v;
    if (jt >= 98) {
      v = -1e30f;                            // pad mask: exp2 -> 0
    } else {
      float rp = 0.f;
      if (i < 98) {
        int di = i / 49, ri_ = i - di * 49, hi = ri_ / 7, wi_ = ri_ - hi * 7;
        int dj = jt / 49, rj_ = jt - dj * 49, hj = rj_ / 7, wj = rj_ - hj * 7;
        int rpi = (di - dj + 1) * 169 + (hi - hj + 6) * 13 + (wi_ - wj + 6);
        rp = rpb[rpi * 3 + hd];
      }
      float mk = (region_cls(cls, i) != region_cls(cls, jt)) ? -100.f : 0.f;
      v = (rp + mk) * LOG2E;
    }
    biasF[idx] = v;
  }
}

// ---------------- K1234: LN1 + roll + QKV + attention + proj + residual ----------------
__global__ __launch_bounds__(512, 1) void k1234_attn(
    const float* __restrict__ x, const float* __restrict__ n1w, const float* __restrict__ n1b,
    const __bf16* __restrict__ wqkv, const float* __restrict__ qkvb,
    const f32x4* __restrict__ biasF, const __bf16* __restrict__ wproj,
    const float* __restrict__ projb, float* __restrict__ x2) {
  int wi = blockIdx.x;
  int tid = threadIdx.x;
  int wave = tid >> 6, l = tid & 63, col = l & 15, gq = l >> 4;
  __shared__ __bf16 win_lds[112][104];  // A out / B in; C writes attnO here; D reads
  __shared__ __bf16 Q_lds[112][104];
  __shared__ __bf16 K_lds[112][104];
  __shared__ __bf16 Vt_lds[96][136];    // 136-pad: vf reads reach col 127; 112..127 zeroed
  __shared__ __bf16 p_lds[8][16][136];  // per-wave P tile

  // ---- phase A: LN1 + roll-gather (packed b128 stores) ----
  if (tid < 392) {
    int row = tid >> 2, cq = (tid & 3) * 24;
    const float* src = x + (size_t)src_tok(wi, row) * 96 + cq;
    float v[24];
    float sm = 0.f, sq = 0.f;
#pragma unroll
    for (int i = 0; i < 6; i++) {
      f32x4 u = *(const f32x4*)(src + 4 * i);
#pragma unroll
      for (int k = 0; k < 4; k++) { v[4 * i + k] = u[k]; sm += u[k]; sq += u[k] * u[k]; }
    }
    sm += __shfl_xor(sm, 1); sq += __shfl_xor(sq, 1);
    sm += __shfl_xor(sm, 2); sq += __shfl_xor(sq, 2);
    float mean = sm * (1.f / 96.f);
    float rstd = rsqrtf(sq * (1.f / 96.f) - mean * mean + 1e-5f);
    __bf16 outv[24];
#pragma unroll
    for (int i = 0; i < 24; i++)
      outv[i] = (__bf16)((v[i] - mean) * rstd * n1w[cq + i] + n1b[cq + i]);
#pragma unroll
    for (int i = 0; i < 3; i++)
      *(bf16x8*)&win_lds[row][cq + 8 * i] = *(bf16x8*)&outv[8 * i];
  } else {
    int z = tid - 392;  // 120 threads: zero pad rows of win, pad token-cols of Vt
    for (int e = z; e < 1344; e += 120) { int r = e / 96; win_lds[98 + r][e - r * 96] = (__bf16)0.f; }
    for (int e = z; e < 1536; e += 120) Vt_lds[e >> 4][112 + (e & 15)] = (__bf16)0.f;
  }
  __syncthreads();

  // ---- phase B: QKV GEMM (waves 0..5) ----
  // Waves 0-3 (Q,K): TRANSPOSED mfma(bb, a) -> lane holds 4 consecutive output
  // dims for one token -> 21 packed b64 stores (was 84 scalar). Waves 4-5 (V):
  // original orientation, token-packed b64 stores into dim-major Vt.
  if (wave < 6) {
    f32x4 acc[7][3] = {};
    bool isQK = (wave < 4);
#pragma unroll
    for (int kk = 0; kk < 3; kk++) {
      bf16x8 a[7], bb[3];
#pragma unroll
      for (int mt = 0; mt < 7; mt++)
        a[mt] = *(const bf16x8*)&win_lds[16 * mt + col][32 * kk + 8 * gq];
#pragma unroll
      for (int t = 0; t < 3; t++)
        bb[t] = *(const bf16x8*)(wqkv + (size_t)(wave * 48 + 16 * t + col) * 96 + 32 * kk + 8 * gq);
#pragma unroll
      for (int mt = 0; mt < 7; mt++)
#pragma unroll
        for (int t = 0; t < 3; t++)
          acc[mt][t] = isQK ? mfma16(bb[t], a[mt], acc[mt][t])
                            : mfma16(a[mt], bb[t], acc[mt][t]);
    }
    if (isQK) {
      // lane: token = 16mt+col, dims n = wave*48+16t+4gq+j (4 consecutive)
#pragma unroll
      for (int t = 0; t < 3; t++) {
        int nb = wave * 48 + 16 * t + 4 * gq;
        f32x4 b4 = *(const f32x4*)(qkvb + nb);
        int isK = nb >= 96;
        int cb = nb - (isK ? 96 : 0);
#pragma unroll
        for (int mt = 0; mt < 7; mt++) {
          bf16x4 pk;
#pragma unroll
          for (int j = 0; j < 4; j++) pk[j] = (__bf16)(acc[mt][t][j] + b4[j]);
          if (isK) *(bf16x4*)&K_lds[16 * mt + col][cb] = pk;
          else     *(bf16x4*)&Q_lds[16 * mt + col][cb] = pk;
        }
      }
    } else {
      // V: lane holds 4 consecutive tokens for one dim -> pack along tokens
#pragma unroll
      for (int t = 0; t < 3; t++) {
        int n = wave * 48 + 16 * t + col;
        float bias = qkvb[n];
        int c = n - 192;
#pragma unroll
        for (int mt = 0; mt < 7; mt++) {
          bf16x4 pk;
#pragma unroll
          for (int j = 0; j < 4; j++) pk[j] = (__bf16)(acc[mt][t][j] + bias);
          *(bf16x4*)&Vt_lds[c][16 * mt + 4 * gq] = pk;
        }
      }
    }
  }
  __syncthreads();

  // ---- phase C: attention, 21 (head,mt) tiles over 8 waves (max 3 each) ----
  {
    {
      int rr = l >> 2, cc = 112 + ((l & 3) << 2);
      *(uint2*)&p_lds[wave][rr][cc] = make_uint2(0u, 0u);
    }
    int cls = ((((wi >> 8) & 3) == 3) ? 4 : 0) | ((((wi >> 4) & 15) == 15) ? 2 : 0) |
              (((wi & 15) == 15) ? 1 : 0);
    int ntiles = (wave < 6) ? 3 : (wave == 6 ? 2 : 1);
    bf16x8 kf[7], vf[2][4];
    int cur_hd = -1;
#pragma unroll 1
    for (int s = 0; s < ntiles; s++) {
      int hd, mt;
      if (wave < 6)      { hd = wave >> 1; mt = ((wave & 1) ? 4 : 0) + s; }
      else if (wave == 6){ hd = s;         mt = 3; }
      else               { hd = 2;         mt = 3; }
      if (hd != cur_hd) {
        cur_hd = hd;
#pragma unroll
        for (int nt = 0; nt < 7; nt++)
          kf[nt] = *(const bf16x8*)&K_lds[16 * nt + col][hd * 32 + 8 * gq];
#pragma unroll
        for (int nt = 0; nt < 2; nt++)
#pragma unroll
          for (int ks = 0; ks < 4; ks++)
            vf[nt][ks] = *(const bf16x8*)&Vt_lds[hd * 32 + 16 * nt + col][32 * ks + 8 * gq];
      }
      const f32x4* bfr = biasF + (size_t)((cls * 3 + hd) * 49) * 64 + l;
      bf16x8 qf = *(const bf16x8*)&Q_lds[16 * mt + col][hd * 32 + 8 * gq];
      float sum0 = 0.f, sum1 = 0.f, sum2 = 0.f, sum3 = 0.f;
#pragma unroll
      for (int nt = 0; nt < 7; nt++) {
        f32x4 sv = mfma16(qf, kf[nt], bfr[(mt * 7 + nt) * 64]);
        float e0 = fast_exp2(sv[0]); sum0 += e0;
        float e1 = fast_exp2(sv[1]); sum1 += e1;
        float e2 = fast_exp2(sv[2]); sum2 += e2;
        float e3 = fast_exp2(sv[3]); sum3 += e3;
        p_lds[wave][4 * gq + 0][16 * nt + col] = (__bf16)e0;
        p_lds[wave][4 * gq + 1][16 * nt + col] = (__bf16)e1;
        p_lds[wave][4 * gq + 2][16 * nt + col] = (__bf16)e2;
        p_lds[wave][4 * gq + 3][16 * nt + col] = (__bf16)e3;
      }
#pragma unroll
      for (int m = 1; m < 16; m <<= 1) {
        sum0 += __shfl_xor(sum0, m, 16);
        sum1 += __shfl_xor(sum1, m, 16);
        sum2 += __shfl_xor(sum2, m, 16);
        sum3 += __shfl_xor(sum3, m, 16);
      }
      f32x4 oacc0 = {}, oacc1 = {};
#pragma unroll
      for (int ks = 0; ks < 4; ks++) {
        bf16x8 pa = *(const bf16x8*)&p_lds[wave][col][32 * ks + 8 * gq];
        oacc0 = mfma16(pa, vf[0][ks], oacc0);
        oacc1 = mfma16(pa, vf[1][ks], oacc1);
      }
      float inv0 = fast_rcp(sum0), inv1 = fast_rcp(sum1), inv2 = fast_rcp(sum2), inv3 = fast_rcp(sum3);
      int ibase = 16 * mt + 4 * gq;
      // attnO -> win_lds (win dead after phase B)
      win_lds[ibase + 0][hd * 32 + col]      = (__bf16)(oacc0[0] * inv0);
      win_lds[ibase + 1][hd * 32 + col]      = (__bf16)(oacc0[1] * inv1);
      win_lds[ibase + 2][hd * 32 + col]      = (__bf16)(oacc0[2] * inv2);
      win_lds[ibase + 3][hd * 32 + col]      = (__bf16)(oacc0[3] * inv3);
      win_lds[ibase + 0][hd * 32 + 16 + col] = (__bf16)(oacc1[0] * inv0);
      win_lds[ibase + 1][hd * 32 + 16 + col] = (__bf16)(oacc1[1] * inv1);
      win_lds[ibase + 2][hd * 32 + 16 + col] = (__bf16)(oacc1[2] * inv2);
      win_lds[ibase + 3][hd * 32 + 16 + col] = (__bf16)(oacc1[3] * inv3);
    }
  }
  __syncthreads();

  // ---- phase D: proj + scatter residual (waves 0..5, 16 out-cols each) ----
  // (round-19 version: direct mfma(a,bb) + per-element src_tok scatter)
  if (wave < 6) {
    f32x4 acc[7] = {};
#pragma unroll
    for (int kk = 0; kk < 3; kk++) {
      bf16x8 bb = *(const bf16x8*)(wproj + (size_t)(16 * wave + col) * 96 + 32 * kk + 8 * gq);
#pragma unroll
      for (int mt = 0; mt < 7; mt++) {
        bf16x8 a = *(const bf16x8*)&win_lds[16 * mt + col][32 * kk + 8 * gq];
        acc[mt] = mfma16(a, bb, acc[mt]);
      }
    }
    int c = 16 * wave + col;
    float pb = projb[c];
#pragma unroll
    for (int mt = 0; mt < 7; mt++) {
#pragma unroll
      for (int j = 0; j < 4; j++) {
        int i = 16 * mt + 4 * gq + j;
        if (i < 98) {
          size_t s = (size_t)src_tok(wi, i);
          x2[s * 96 + c] = x[s * 96 + c] + acc[mt][j] + pb;
        }
      }
    }
  }
}

// ---------------- K567: fused LN2 + FC1 + GELU + FC2 + residual ----------------
// 128-row blocks (grid 1568), single-buffered weight staging, 66.5 KB -> 2 blocks/CU.
__global__ __launch_bounds__(512, 2) void k567_mlp(
    const float* __restrict__ n2w, const float* __restrict__ n2b,
    const __bf16* __restrict__ wfc1, const float* __restrict__ fc1b,
    const __bf16* __restrict__ wfc2, const float* __restrict__ fc2b,
    float* __restrict__ x2) {
  int tid = threadIdx.x;
  int wave = tid >> 6, l = tid & 63, col = l & 15, gq = l >> 4;
  size_t rowbase = (size_t)blockIdx.x * 128 + wave * 16;
  __shared__ __bf16 wbuf[2][96][104];  // [W1/W2][row][col pad 104]
  __shared__ __bf16 htl[8][16][104];   // wave-private hidden tile

  // ---- LN2 -> register A-fragments (row col of this wave's 16) ----
  bf16x8 afr[3];
  {
    float v[24];
    float sm = 0.f, sq = 0.f;
    const float* src = x2 + (rowbase + col) * 96 + 8 * gq;
#pragma unroll
    for (int kk = 0; kk < 3; kk++) {
      f32x4 u0 = *(const f32x4*)(src + 32 * kk);
      f32x4 u1 = *(const f32x4*)(src + 32 * kk + 4);
#pragma unroll
      for (int k = 0; k < 4; k++) {
        v[8 * kk + k] = u0[k];     sm += u0[k]; sq += u0[k] * u0[k];
        v[8 * kk + 4 + k] = u1[k]; sm += u1[k]; sq += u1[k] * u1[k];
      }
    }
    sm += __shfl_xor(sm, 16); sq += __shfl_xor(sq, 16);
    sm += __shfl_xor(sm, 32); sq += __shfl_xor(sq, 32);
    float mean = sm * (1.f / 96.f);
    float rstd = rsqrtf(sq * (1.f / 96.f) - mean * mean + 1e-5f);
#pragma unroll
    for (int kk = 0; kk < 3; kk++) {
      f32x4 w0 = *(const f32x4*)(n2w + 32 * kk + 8 * gq);
      f32x4 w1 = *(const f32x4*)(n2w + 32 * kk + 8 * gq + 4);
      f32x4 b0 = *(const f32x4*)(n2b + 32 * kk + 8 * gq);
      f32x4 b1 = *(const f32x4*)(n2b + 32 * kk + 8 * gq + 4);
#pragma unroll
      for (int k = 0; k < 4; k++) {
        afr[kk][k]     = (__bf16)((v[8 * kk + k]     - mean) * rstd * w0[k] + b0[k]);
        afr[kk][4 + k] = (__bf16)((v[8 * kk + 4 + k] - mean) * rstd * w1[k] + b1[k]);
      }
    }
  }

  // cooperative weight staging: 2304 16B units per quarter (1152 W1 + 1152 W2)
#define STAGE_LOAD(qq, st)                                                        \
  {                                                                               \
    _Pragma("unroll")                                                             \
    for (int i = 0; i < 4; i++) {                                                 \
      int u = tid + 512 * i;                                                      \
      int which = u >= 1152; int uu = u - which * 1152;                           \
      int row = uu / 12, c = uu - row * 12;                                       \
      const __bf16* g = which ? (wfc2 + (size_t)row * 384 + (qq) * 96 + c * 8)    \
                              : (wfc1 + ((size_t)((qq) * 96 + row)) * 96 + c * 8);\
      st[i] = *(const bf16x8*)g;                                                  \
    }                                                                             \
    if (tid < 256) {                                                              \
      int u = 2048 + tid;                                                         \
      int row = (u - 1152) / 12, c = (u - 1152) - row * 12;                       \
      st[4] = *(const bf16x8*)(wfc2 + (size_t)row * 384 + (qq) * 96 + c * 8);     \
    }                                                                             \
  }
#define STAGE_WRITE(st)                                                           \
  {                                                                               \
    _Pragma("unroll")                                                             \
    for (int i = 0; i < 4; i++) {                                                 \
      int u = tid + 512 * i;                                                      \
      int which = u >= 1152; int uu = u - which * 1152;                           \
      int row = uu / 12, c = uu - row * 12;                                       \
      *(bf16x8*)&wbuf[which][row][c * 8] = st[i];                                 \
    }                                                                             \
    if (tid < 256) {                                                              \
      int u = 2048 + tid;                                                         \
      int row = (u - 1152) / 12, c = (u - 1152) - row * 12;                       \
      *(bf16x8*)&wbuf[1][row][c * 8] = st[4];                                     \
    }                                                                             \
  }

  // prologue: stage quarter 0
  {
    bf16x8 st[5];
    STAGE_LOAD(0, st);
    STAGE_WRITE(st);
  }
  __syncthreads();

  f32x4 oc[6] = {};
#pragma unroll 1
  for (int q = 0; q < 4; q++) {
    bf16x8 st[5];
    if (q < 3) STAGE_LOAD(q + 1, st);      // issue early: hides under MFMA
    // ---- stage 1: acc = ntile @ W1_q^T ----
    f32x4 acc[6] = {};
#pragma unroll
    for (int kk = 0; kk < 3; kk++) {
      bf16x8 bb[6];
#pragma unroll
      for (int t = 0; t < 6; t++)
        bb[t] = *(const bf16x8*)&wbuf[0][16 * t + col][32 * kk + 8 * gq];
#pragma unroll
      for (int t = 0; t < 6; t++) acc[t] = mfma16(afr[kk], bb[t], acc[t]);
    }
    // ---- gelu -> wave-private htl ----
#pragma unroll
    for (int t = 0; t < 6; t++) {
      float bv = fc1b[q * 96 + 16 * t + col];
#pragma unroll
      for (int j = 0; j < 4; j++)
        htl[wave][4 * gq + j][16 * t + col] = (__bf16)fast_gelu(acc[t][j] + bv);
    }
    // ---- stage 2: oc += htl @ W2_q^T ----
#pragma unroll
    for (int kk = 0; kk < 3; kk++) {
      bf16x8 a0 = *(const bf16x8*)&htl[wave][col][32 * kk + 8 * gq];
      bf16x8 bb[6];
#pragma unroll
      for (int t = 0; t < 6; t++)
        bb[t] = *(const bf16x8*)&wbuf[1][16 * t + col][32 * kk + 8 * gq];
#pragma unroll
      for (int t = 0; t < 6; t++) oc[t] = mfma16(a0, bb[t], oc[t]);
    }
    __syncthreads();                       // all waves done READING wbuf for q
    if (q < 3) {
      STAGE_WRITE(st);                     // overwrite with quarter q+1
      __syncthreads();                     // wbuf ready
    }
  }
  // ---- epilogue: x2 += oc + b2 ----
#pragma unroll
  for (int t = 0; t < 6; t++) {
    float bv = fc2b[16 * t + col];
#pragma unroll
    for (int j = 0; j < 4; j++) {
      size_t row = rowbase + 4 * gq + j;
      x2[row * 96 + 16 * t + col] = x2[row * 96 + 16 * t + col] + oc[t][j] + bv;
    }
  }
#undef STAGE_LOAD
#undef STAGE_WRITE
}

// ---------------- launcher ----------------
// ws layout (bytes):
#define O_WQKV   0L
#define O_WPROJ  55296L
#define O_WFC1   73728L
#define O_WFC2   147456L
#define O_QKVB   221184L
#define O_BIASF  222336L     // 1,204,224 B

extern "C" void kernel_launch(void* const* d_in, const int* in_sizes, int n_in,
                              void* d_out, int out_size, void* d_ws, size_t ws_size,
                              hipStream_t stream) {
  const float* x     = (const float*)d_in[0];
  const float* n1w   = (const float*)d_in[1];
  const float* n1b   = (const float*)d_in[2];
  const float* qkvw  = (const float*)d_in[3];
  const float* qkvb  = (const float*)d_in[4];
  const float* rpb   = (const float*)d_in[5];
  const float* projw = (const float*)d_in[6];
  const float* projb = (const float*)d_in[7];
  const float* n2w   = (const float*)d_in[8];
  const float* n2b   = (const float*)d_in[9];
  const float* fc1w  = (const float*)d_in[10];
  const float* fc1b  = (const float*)d_in[11];
  const float* fc2w  = (const float*)d_in[12];
  const float* fc2b  = (const float*)d_in[13];

  char* ws = (char*)d_ws;
  __bf16* wqkv   = (__bf16*)(ws + O_WQKV);
  __bf16* wproj  = (__bf16*)(ws + O_WPROJ);
  __bf16* wfc1   = (__bf16*)(ws + O_WFC1);
  __bf16* wfc2   = (__bf16*)(ws + O_WFC2);
  float*  qkvb_s = (float*)(ws + O_QKVB);
  float*  biasF  = (float*)(ws + O_BIASF);
  float*  x2     = (float*)d_out;          // residual spine lives in d_out

  k0_prep<<<1610, 256, 0, stream>>>(qkvw, qkvb, rpb, projw, fc1w, fc2w,
                                    wqkv, qkvb_s, wproj, wfc1, wfc2, biasF);
  k1234_attn<<<2048, 512, 0, stream>>>(x, n1w, n1b, wqkv, qkvb_s,
                                       (const f32x4*)biasF, wproj, projb, x2);
  k567_mlp<<<1568, 512, 0, stream>>>(n2w, n2b, wfc1, fc1b, wfc2, fc2b, x2);
}

// Round 22
// 180.634 us; speedup vs baseline: 1.1128x; 1.0570x over previous
//
#include <hip/hip_runtime.h>
#include <hip/hip_bf16.h>

// Swin3D block, MI355X. FINAL configuration (session best, 183.3 us):
// k1234: LN1+QKV+attn+proj+residual, one block/window, packed phase-A b128
// stores, packed V b64 stores, scalar Q/K stores (transposed-MFMA packing
// measured slower), direct phase-D scatter.
// k567: LN2+MLP, single-buffered block-staged weights (66.5 KB -> 2 blocks/CU).
// fp32 residual spine lives in d_out.

typedef __bf16 bf16x8 __attribute__((ext_vector_type(8)));
typedef __bf16 bf16x4 __attribute__((ext_vector_type(4)));
typedef float f32x4 __attribute__((ext_vector_type(4)));

#define SCALE_Q 0.17677669529663687f
#define LOG2E   1.4426950408889634f
#define SCALE_QE (SCALE_Q * LOG2E)

static __device__ __forceinline__ f32x4 mfma16(bf16x8 a, bf16x8 b, f32x4 c) {
  return __builtin_amdgcn_mfma_f32_16x16x32_bf16(a, b, c, 0, 0, 0);
}

static __device__ __forceinline__ float fast_exp2(float x) {
#if __has_builtin(__builtin_amdgcn_exp2f)
  return __builtin_amdgcn_exp2f(x);
#else
  return exp2f(x);
#endif
}
static __device__ __forceinline__ float fast_rcp(float x) {
#if __has_builtin(__builtin_amdgcn_rcpf)
  return __builtin_amdgcn_rcpf(x);
#else
  return 1.f / x;
#endif
}

// tanh-approx GELU in sigmoid form. |err| vs exact < 1e-3 (contracted by FC2).
static __device__ __forceinline__ float fast_gelu(float x) {
  float e = fast_exp2(x * fmaf(-0.1029445213f, x * x, -2.3022077385f));
  return x * fast_rcp(1.f + e);
}

// window wi (0..2047), token n (0..97) -> flat spatial token index in x (rolled by +1,+3,+3)
static __device__ __forceinline__ int src_tok(int wi, int n) {
  int b = wi >> 10, r = wi & 1023;
  int d0 = r >> 8, h0 = (r >> 4) & 15, w0 = r & 15;
  int dd = n / 49, rem = n - dd * 49, hh = rem / 7, ww = rem - hh * 7;
  int d = (d0 * 2 + dd + 1) & 7;
  int h = h0 * 7 + hh + 3; if (h >= 112) h -= 112;
  int w = w0 * 7 + ww + 3; if (w >= 112) w -= 112;
  return ((b * 8 + d) * 112 + h) * 112 + w;
}

// region id in the SHIFTED frame, parameterized by window class bits
// (bit2: d0==3, bit1: h0==15, bit0: w0==15). Valid for n in [0,112).
static __device__ __forceinline__ int region_cls(int cls, int n) {
  int dd = n / 49, rem = n - dd * 49, hh = rem / 7, ww = rem - hh * 7;
  int dr = (cls & 4) ? dd + 1 : 0;
  int hr = (cls & 2) ? (hh < 4 ? 1 : 2) : 0;
  int wr = (cls & 1) ? (ww < 4 ? 1 : 2) : 0;
  return dr * 9 + hr * 3 + wr;
}

// ---------------- K0: weight prep + MFMA-fragment-ordered bias table ----------------
__global__ __launch_bounds__(256) void k0_prep(
    const float* __restrict__ qkv_w, const float* __restrict__ qkv_b,
    const float* __restrict__ rpb, const float* __restrict__ proj_w,
    const float* __restrict__ fc1_w, const float* __restrict__ fc2_w,
    __bf16* __restrict__ wqkv, float* __restrict__ qkvb_s,
    __bf16* __restrict__ wproj, __bf16* __restrict__ wfc1, __bf16* __restrict__ wfc2,
    float* __restrict__ biasF) {
  int idx = blockIdx.x * 256 + threadIdx.x;
  if (idx < 27648) { // qkv_w (288x96): fold q-scale * log2e into q rows
    int row = idx / 96; float v = qkv_w[idx];
    wqkv[idx] = (__bf16)(row < 96 ? v * SCALE_QE : v); return;
  }
  idx -= 27648;
  if (idx < 9216) { wproj[idx] = (__bf16)proj_w[idx]; return; }
  idx -= 9216;
  if (idx < 36864) { wfc1[idx] = (__bf16)fc1_w[idx]; return; }
  idx -= 36864;
  if (idx < 36864) { wfc2[idx] = (__bf16)fc2_w[idx]; return; }
  idx -= 36864;
  if (idx < 288) { float v = qkv_b[idx]; qkvb_s[idx] = idx < 96 ? v * SCALE_QE : v; return; }
  idx -= 288;
  if (idx < 301056) { // 8*3*49*64*4
    int j = idx & 3, lane = (idx >> 2) & 63, t = idx >> 8;
    int nt = t % 7, mt = (t / 7) % 7, hd = (t / 49) % 3, cls = t / 147;
    int i = 16 * mt + 4 * (lane >> 4) + j;   // query row 0..111
    int jt = 16 * nt + (lane & 15);          // key col 0..111
    float v;
    if (jt >= 98) {
      v = -1e30f;                            // pad mask: exp2 -> 0
    } else {
      float rp = 0.f;
      if (i < 98) {
        int di = i / 49, ri_ = i - di * 49, hi = ri_ / 7, wi_ = ri_ - hi * 7;
        int dj = jt / 49, rj_ = jt - dj * 49, hj = rj_ / 7, wj = rj_ - hj * 7;
        int rpi = (di - dj + 1) * 169 + (hi - hj + 6) * 13 + (wi_ - wj + 6);
        rp = rpb[rpi * 3 + hd];
      }
      float mk = (region_cls(cls, i) != region_cls(cls, jt)) ? -100.f : 0.f;
      v = (rp + mk) * LOG2E;
    }
    biasF[idx] = v;
  }
}

// ---------------- K1234: LN1 + roll + QKV + attention + proj + residual ----------------
__global__ __launch_bounds__(512, 1) void k1234_attn(
    const float* __restrict__ x, const float* __restrict__ n1w, const float* __restrict__ n1b,
    const __bf16* __restrict__ wqkv, const float* __restrict__ qkvb,
    const f32x4* __restrict__ biasF, const __bf16* __restrict__ wproj,
    const float* __restrict__ projb, float* __restrict__ x2) {
  int wi = blockIdx.x;
  int tid = threadIdx.x;
  int wave = tid >> 6, l = tid & 63, col = l & 15, gq = l >> 4;
  __shared__ __bf16 win_lds[112][104];  // A out / B in; C writes attnO here; D reads
  __shared__ __bf16 Q_lds[112][104];
  __shared__ __bf16 K_lds[112][104];
  __shared__ __bf16 Vt_lds[96][136];    // 136-pad: vf reads reach col 127; 112..127 zeroed
  __shared__ __bf16 p_lds[8][16][136];  // per-wave P tile

  // ---- phase A: LN1 + roll-gather (packed b128 stores) ----
  if (tid < 392) {
    int row = tid >> 2, cq = (tid & 3) * 24;
    const float* src = x + (size_t)src_tok(wi, row) * 96 + cq;
    float v[24];
    float sm = 0.f, sq = 0.f;
#pragma unroll
    for (int i = 0; i < 6; i++) {
      f32x4 u = *(const f32x4*)(src + 4 * i);
#pragma unroll
      for (int k = 0; k < 4; k++) { v[4 * i + k] = u[k]; sm += u[k]; sq += u[k] * u[k]; }
    }
    sm += __shfl_xor(sm, 1); sq += __shfl_xor(sq, 1);
    sm += __shfl_xor(sm, 2); sq += __shfl_xor(sq, 2);
    float mean = sm * (1.f / 96.f);
    float rstd = rsqrtf(sq * (1.f / 96.f) - mean * mean + 1e-5f);
    __bf16 outv[24];
#pragma unroll
    for (int i = 0; i < 24; i++)
      outv[i] = (__bf16)((v[i] - mean) * rstd * n1w[cq + i] + n1b[cq + i]);
    // 208*row + 2*cq is 16B-aligned (cq multiple of 24 -> 48B; 208 mult of 16)
#pragma unroll
    for (int i = 0; i < 3; i++)
      *(bf16x8*)&win_lds[row][cq + 8 * i] = *(bf16x8*)&outv[8 * i];
  } else {
    int z = tid - 392;  // 120 threads: zero pad rows of win, pad token-cols of Vt
    for (int e = z; e < 1344; e += 120) { int r = e / 96; win_lds[98 + r][e - r * 96] = (__bf16)0.f; }
    for (int e = z; e < 1536; e += 120) Vt_lds[e >> 4][112 + (e & 15)] = (__bf16)0.f;
  }
  __syncthreads();

  // ---- phase B: QKV GEMM (waves 0..5) ----
  if (wave < 6) {
    f32x4 acc[7][3] = {};
#pragma unroll
    for (int kk = 0; kk < 3; kk++) {
      bf16x8 a[7], bb[3];
#pragma unroll
      for (int mt = 0; mt < 7; mt++)
        a[mt] = *(const bf16x8*)&win_lds[16 * mt + col][32 * kk + 8 * gq];
#pragma unroll
      for (int t = 0; t < 3; t++)
        bb[t] = *(const bf16x8*)(wqkv + (size_t)(wave * 48 + 16 * t + col) * 96 + 32 * kk + 8 * gq);
#pragma unroll
      for (int mt = 0; mt < 7; mt++)
#pragma unroll
        for (int t = 0; t < 3; t++) acc[mt][t] = mfma16(a[mt], bb[t], acc[mt][t]);
    }
#pragma unroll
    for (int t = 0; t < 3; t++) {
      int n = wave * 48 + 16 * t + col;
      float bias = qkvb[n];
      int which = n / 96, c = n - which * 96;   // wave-uniform `which`
      if (which == 2) {
        // V: 4 consecutive rows per lane -> one b64 store per mt
#pragma unroll
        for (int mt = 0; mt < 7; mt++) {
          bf16x4 pk;
#pragma unroll
          for (int j = 0; j < 4; j++) pk[j] = (__bf16)(acc[mt][t][j] + bias);
          *(bf16x4*)&Vt_lds[c][16 * mt + 4 * gq] = pk;
        }
      } else {
#pragma unroll
        for (int mt = 0; mt < 7; mt++) {
#pragma unroll
          for (int j = 0; j < 4; j++) {
            int row = 16 * mt + 4 * gq + j;
            float v = acc[mt][t][j] + bias;
            if (which == 0) Q_lds[row][c] = (__bf16)v;
            else            K_lds[row][c] = (__bf16)v;
          }
        }
      }
    }
  }
  __syncthreads();

  // ---- phase C: attention, 21 (head,mt) tiles over 8 waves (max 3 each) ----
  {
    {
      int rr = l >> 2, cc = 112 + ((l & 3) << 2);
      *(uint2*)&p_lds[wave][rr][cc] = make_uint2(0u, 0u);
    }
    int cls = ((((wi >> 8) & 3) == 3) ? 4 : 0) | ((((wi >> 4) & 15) == 15) ? 2 : 0) |
              (((wi & 15) == 15) ? 1 : 0);
    int ntiles = (wave < 6) ? 3 : (wave == 6 ? 2 : 1);
    bf16x8 kf[7], vf[2][4];
    int cur_hd = -1;
#pragma unroll 1
    for (int s = 0; s < ntiles; s++) {
      int hd, mt;
      if (wave < 6)      { hd = wave >> 1; mt = ((wave & 1) ? 4 : 0) + s; }
      else if (wave == 6){ hd = s;         mt = 3; }
      else               { hd = 2;         mt = 3; }
      if (hd != cur_hd) {
        cur_hd = hd;
#pragma unroll
        for (int nt = 0; nt < 7; nt++)
          kf[nt] = *(const bf16x8*)&K_lds[16 * nt + col][hd * 32 + 8 * gq];
#pragma unroll
        for (int nt = 0; nt < 2; nt++)
#pragma unroll
          for (int ks = 0; ks < 4; ks++)
            vf[nt][ks] = *(const bf16x8*)&Vt_lds[hd * 32 + 16 * nt + col][32 * ks + 8 * gq];
      }
      const f32x4* bfr = biasF + (size_t)((cls * 3 + hd) * 49) * 64 + l;
      bf16x8 qf = *(const bf16x8*)&Q_lds[16 * mt + col][hd * 32 + 8 * gq];
      float sum0 = 0.f, sum1 = 0.f, sum2 = 0.f, sum3 = 0.f;
#pragma unroll
      for (int nt = 0; nt < 7; nt++) {
        f32x4 sv = mfma16(qf, kf[nt], bfr[(mt * 7 + nt) * 64]);
        float e0 = fast_exp2(sv[0]); sum0 += e0;
        float e1 = fast_exp2(sv[1]); sum1 += e1;
        float e2 = fast_exp2(sv[2]); sum2 += e2;
        float e3 = fast_exp2(sv[3]); sum3 += e3;
        p_lds[wave][4 * gq + 0][16 * nt + col] = (__bf16)e0;
        p_lds[wave][4 * gq + 1][16 * nt + col] = (__bf16)e1;
        p_lds[wave][4 * gq + 2][16 * nt + col] = (__bf16)e2;
        p_lds[wave][4 * gq + 3][16 * nt + col] = (__bf16)e3;
      }
#pragma unroll
      for (int m = 1; m < 16; m <<= 1) {
        sum0 += __shfl_xor(sum0, m, 16);
        sum1 += __shfl_xor(sum1, m, 16);
        sum2 += __shfl_xor(sum2, m, 16);
        sum3 += __shfl_xor(sum3, m, 16);
      }
      f32x4 oacc0 = {}, oacc1 = {};
#pragma unroll
      for (int ks = 0; ks < 4; ks++) {
        bf16x8 pa = *(const bf16x8*)&p_lds[wave][col][32 * ks + 8 * gq];
        oacc0 = mfma16(pa, vf[0][ks], oacc0);
        oacc1 = mfma16(pa, vf[1][ks], oacc1);
      }
      float inv0 = fast_rcp(sum0), inv1 = fast_rcp(sum1), inv2 = fast_rcp(sum2), inv3 = fast_rcp(sum3);
      int ibase = 16 * mt + 4 * gq;
      // attnO -> win_lds (win dead after phase B)
      win_lds[ibase + 0][hd * 32 + col]      = (__bf16)(oacc0[0] * inv0);
      win_lds[ibase + 1][hd * 32 + col]      = (__bf16)(oacc0[1] * inv1);
      win_lds[ibase + 2][hd * 32 + col]      = (__bf16)(oacc0[2] * inv2);
      win_lds[ibase + 3][hd * 32 + col]      = (__bf16)(oacc0[3] * inv3);
      win_lds[ibase + 0][hd * 32 + 16 + col] = (__bf16)(oacc1[0] * inv0);
      win_lds[ibase + 1][hd * 32 + 16 + col] = (__bf16)(oacc1[1] * inv1);
      win_lds[ibase + 2][hd * 32 + 16 + col] = (__bf16)(oacc1[2] * inv2);
      win_lds[ibase + 3][hd * 32 + 16 + col] = (__bf16)(oacc1[3] * inv3);
    }
  }
  __syncthreads();

  // ---- phase D: proj + scatter residual (waves 0..5, 16 out-cols each) ----
  if (wave < 6) {
    f32x4 acc[7] = {};
#pragma unroll
    for (int kk = 0; kk < 3; kk++) {
      bf16x8 bb = *(const bf16x8*)(wproj + (size_t)(16 * wave + col) * 96 + 32 * kk + 8 * gq);
#pragma unroll
      for (int mt = 0; mt < 7; mt++) {
        bf16x8 a = *(const bf16x8*)&win_lds[16 * mt + col][32 * kk + 8 * gq];
        acc[mt] = mfma16(a, bb, acc[mt]);
      }
    }
    int c = 16 * wave + col;
    float pb = projb[c];
#pragma unroll
    for (int mt = 0; mt < 7; mt++) {
#pragma unroll
      for (int j = 0; j < 4; j++) {
        int i = 16 * mt + 4 * gq + j;
        if (i < 98) {
          size_t s = (size_t)src_tok(wi, i);
          x2[s * 96 + c] = x[s * 96 + c] + acc[mt][j] + pb;
        }
      }
    }
  }
}

// ---------------- K567: fused LN2 + FC1 + GELU + FC2 + residual ----------------
// 128-row blocks (grid 1568), single-buffered weight staging, 66.5 KB -> 2 blocks/CU.
__global__ __launch_bounds__(512, 2) void k567_mlp(
    const float* __restrict__ n2w, const float* __restrict__ n2b,
    const __bf16* __restrict__ wfc1, const float* __restrict__ fc1b,
    const __bf16* __restrict__ wfc2, const float* __restrict__ fc2b,
    float* __restrict__ x2) {
  int tid = threadIdx.x;
  int wave = tid >> 6, l = tid & 63, col = l & 15, gq = l >> 4;
  size_t rowbase = (size_t)blockIdx.x * 128 + wave * 16;
  __shared__ __bf16 wbuf[2][96][104];  // [W1/W2][row][col pad 104]
  __shared__ __bf16 htl[8][16][104];   // wave-private hidden tile

  // ---- LN2 -> register A-fragments (row col of this wave's 16) ----
  bf16x8 afr[3];
  {
    float v[24];
    float sm = 0.f, sq = 0.f;
    const float* src = x2 + (rowbase + col) * 96 + 8 * gq;
#pragma unroll
    for (int kk = 0; kk < 3; kk++) {
      f32x4 u0 = *(const f32x4*)(src + 32 * kk);
      f32x4 u1 = *(const f32x4*)(src + 32 * kk + 4);
#pragma unroll
      for (int k = 0; k < 4; k++) {
        v[8 * kk + k] = u0[k];     sm += u0[k]; sq += u0[k] * u0[k];
        v[8 * kk + 4 + k] = u1[k]; sm += u1[k]; sq += u1[k] * u1[k];
      }
    }
    sm += __shfl_xor(sm, 16); sq += __shfl_xor(sq, 16);
    sm += __shfl_xor(sm, 32); sq += __shfl_xor(sq, 32);
    float mean = sm * (1.f / 96.f);
    float rstd = rsqrtf(sq * (1.f / 96.f) - mean * mean + 1e-5f);
#pragma unroll
    for (int kk = 0; kk < 3; kk++) {
      f32x4 w0 = *(const f32x4*)(n2w + 32 * kk + 8 * gq);
      f32x4 w1 = *(const f32x4*)(n2w + 32 * kk + 8 * gq + 4);
      f32x4 b0 = *(const f32x4*)(n2b + 32 * kk + 8 * gq);
      f32x4 b1 = *(const f32x4*)(n2b + 32 * kk + 8 * gq + 4);
#pragma unroll
      for (int k = 0; k < 4; k++) {
        afr[kk][k]     = (__bf16)((v[8 * kk + k]     - mean) * rstd * w0[k] + b0[k]);
        afr[kk][4 + k] = (__bf16)((v[8 * kk + 4 + k] - mean) * rstd * w1[k] + b1[k]);
      }
    }
  }

  // cooperative weight staging: 2304 16B units per quarter (1152 W1 + 1152 W2)
#define STAGE_LOAD(qq, st)                                                        \
  {                                                                               \
    _Pragma("unroll")                                                             \
    for (int i = 0; i < 4; i++) {                                                 \
      int u = tid + 512 * i;                                                      \
      int which = u >= 1152; int uu = u - which * 1152;                           \
      int row = uu / 12, c = uu - row * 12;                                       \
      const __bf16* g = which ? (wfc2 + (size_t)row * 384 + (qq) * 96 + c * 8)    \
                              : (wfc1 + ((size_t)((qq) * 96 + row)) * 96 + c * 8);\
      st[i] = *(const bf16x8*)g;                                                  \
    }                                                                             \
    if (tid < 256) {                                                              \
      int u = 2048 + tid;                                                         \
      int row = (u - 1152) / 12, c = (u - 1152) - row * 12;                       \
      st[4] = *(const bf16x8*)(wfc2 + (size_t)row * 384 + (qq) * 96 + c * 8);     \
    }                                                                             \
  }
#define STAGE_WRITE(st)                                                           \
  {                                                                               \
    _Pragma("unroll")                                                             \
    for (int i = 0; i < 4; i++) {                                                 \
      int u = tid + 512 * i;                                                      \
      int which = u >= 1152; int uu = u - which * 1152;                           \
      int row = uu / 12, c = uu - row * 12;                                       \
      *(bf16x8*)&wbuf[which][row][c * 8] = st[i];                                 \
    }                                                                             \
    if (tid < 256) {                                                              \
      int u = 2048 + tid;                                                         \
      int row = (u - 1152) / 12, c = (u - 1152) - row * 12;                       \
      *(bf16x8*)&wbuf[1][row][c * 8] = st[4];                                     \
    }                                                                             \
  }

  // prologue: stage quarter 0
  {
    bf16x8 st[5];
    STAGE_LOAD(0, st);
    STAGE_WRITE(st);
  }
  __syncthreads();

  f32x4 oc[6] = {};
#pragma unroll 1
  for (int q = 0; q < 4; q++) {
    bf16x8 st[5];
    if (q < 3) STAGE_LOAD(q + 1, st);      // issue early: hides under MFMA
    // ---- stage 1: acc = ntile @ W1_q^T ----
    f32x4 acc[6] = {};
#pragma unroll
    for (int kk = 0; kk < 3; kk++) {
      bf16x8 bb[6];
#pragma unroll
      for (int t = 0; t < 6; t++)
        bb[t] = *(const bf16x8*)&wbuf[0][16 * t + col][32 * kk + 8 * gq];
#pragma unroll
      for (int t = 0; t < 6; t++) acc[t] = mfma16(afr[kk], bb[t], acc[t]);
    }
    // ---- gelu -> wave-private htl ----
#pragma unroll
    for (int t = 0; t < 6; t++) {
      float bv = fc1b[q * 96 + 16 * t + col];
#pragma unroll
      for (int j = 0; j < 4; j++)
        htl[wave][4 * gq + j][16 * t + col] = (__bf16)fast_gelu(acc[t][j] + bv);
    }
    // ---- stage 2: oc += htl @ W2_q^T ----
#pragma unroll
    for (int kk = 0; kk < 3; kk++) {
      bf16x8 a0 = *(const bf16x8*)&htl[wave][col][32 * kk + 8 * gq];
      bf16x8 bb[6];
#pragma unroll
      for (int t = 0; t < 6; t++)
        bb[t] = *(const bf16x8*)&wbuf[1][16 * t + col][32 * kk + 8 * gq];
#pragma unroll
      for (int t = 0; t < 6; t++) oc[t] = mfma16(a0, bb[t], oc[t]);
    }
    __syncthreads();                       // all waves done READING wbuf for q
    if (q < 3) {
      STAGE_WRITE(st);                     // overwrite with quarter q+1
      __syncthreads();                     // wbuf ready
    }
  }
  // ---- epilogue: x2 += oc + b2 ----
#pragma unroll
  for (int t = 0; t < 6; t++) {
    float bv = fc2b[16 * t + col];
#pragma unroll
    for (int j = 0; j < 4; j++) {
      size_t row = rowbase + 4 * gq + j;
      x2[row * 96 + 16 * t + col] = x2[row * 96 + 16 * t + col] + oc[t][j] + bv;
    }
  }
#undef STAGE_LOAD
#undef STAGE_WRITE
}

// ---------------- launcher ----------------
// ws layout (bytes):
#define O_WQKV   0L
#define O_WPROJ  55296L
#define O_WFC1   73728L
#define O_WFC2   147456L
#define O_QKVB   221184L
#define O_BIASF  222336L     // 1,204,224 B

extern "C" void kernel_launch(void* const* d_in, const int* in_sizes, int n_in,
                              void* d_out, int out_size, void* d_ws, size_t ws_size,
                              hipStream_t stream) {
  const float* x     = (const float*)d_in[0];
  const float* n1w   = (const float*)d_in[1];
  const float* n1b   = (const float*)d_in[2];
  const float* qkvw  = (const float*)d_in[3];
  const float* qkvb  = (const float*)d_in[4];
  const float* rpb   = (const float*)d_in[5];
  const float* projw = (const float*)d_in[6];
  const float* projb = (const float*)d_in[7];
  const float* n2w   = (const float*)d_in[8];
  const float* n2b   = (const float*)d_in[9];
  const float* fc1w  = (const float*)d_in[10];
  const float* fc1b  = (const float*)d_in[11];
  const float* fc2w  = (const float*)d_in[12];
  const float* fc2b  = (const float*)d_in[13];

  char* ws = (char*)d_ws;
  __bf16* wqkv   = (__bf16*)(ws + O_WQKV);
  __bf16* wproj  = (__bf16*)(ws + O_WPROJ);
  __bf16* wfc1   = (__bf16*)(ws + O_WFC1);
  __bf16* wfc2   = (__bf16*)(ws + O_WFC2);
  float*  qkvb_s = (float*)(ws + O_QKVB);
  float*  biasF  = (float*)(ws + O_BIASF);
  float*  x2     = (float*)d_out;          // residual spine lives in d_out

  k0_prep<<<1610, 256, 0, stream>>>(qkvw, qkvb, rpb, projw, fc1w, fc2w,
                                    wqkv, qkvb_s, wproj, wfc1, wfc2, biasF);
  k1234_attn<<<2048, 512, 0, stream>>>(x, n1w, n1b, wqkv, qkvb_s,
                                       (const f32x4*)biasF, wproj, projb, x2);
  k567_mlp<<<1568, 512, 0, stream>>>(n2w, n2b, wfc1, fc1b, wfc2, fc2b, x2);
}